// Round 14
// baseline (218.010 us; speedup 1.0000x reference)
//
#include <hip/hip_runtime.h>
#include <hip/hip_bf16.h>

// VQ-VAE pipeline. Round 25: r24 WON (221.8 -> 211.6us, third straight).
// conv3_quant (~39us) is VALU-bound in the distance phase (VALUBusy 19% >>
// MfmaUtil 5.5%): 256 candidate updates/lane x ~8 VALU ops (packed
// sortable-u32: mul,add,3-op f2ord,and,or,umin) ~= 4k cyc/wave vs ~512 cyc
// of MFMA. Halve it: prep pre-scales c2 by 0.5 (exact pow2 scaling ->
// fl(a/2-b/2)=fl(a-b)/2, ordering AND ties identical), update becomes
// {sd = c2h - aq; cmp; 2x cndmask} into separate float/idx regs (4 ops).
// Butterfly gains an explicit (d,idx) lexicographic tie-break (+~400 ops,
// << 1024 saved). Within-lane ascending-ct strict < keeps first-on-tie =
// packed semantics. +16 VGPR (~104). Everything else = r24 verbatim.
// Tripwires: absmax 6.103516e-05 exact (tie divergence would blow it);
// conv3_quant FETCH ~17MB; if total >= 211 revert to r24 as final.

#define NB 16
#define T0 32768
#define T1 16384
#define T2 8192
#define T3 4096
#define NCODES 512
#define EDIM 64

typedef __attribute__((ext_vector_type(8)))  short short8;
typedef __attribute__((ext_vector_type(16))) float f32x16;
typedef __attribute__((ext_vector_type(16))) unsigned u32x16;
typedef __attribute__((ext_vector_type(4)))  float f32x4;

__device__ __forceinline__ float b2f(short s) {
    unsigned u = ((unsigned)(unsigned short)s) << 16;
    float f; __builtin_memcpy(&f, &u, 4); return f;
}
__device__ __forceinline__ short f2bs(float f) {
    __hip_bfloat16 h = __float2bfloat16(f);
    short s; __builtin_memcpy(&s, &h, 2); return s;
}

// async 16B global->LDS copy (wave-uniform LDS base + lane*16; drained by
// the s_waitcnt vmcnt(0) that __syncthreads() emits)
__device__ __forceinline__ void gload_lds16(const void* g, void* l) {
    __builtin_amdgcn_global_load_lds(
        (const __attribute__((address_space(1))) void*)g,
        (__attribute__((address_space(3))) void*)l, 16, 0, 0);
}

__device__ __forceinline__ float block_sum256(float v) {
    #pragma unroll
    for (int off = 32; off > 0; off >>= 1) v += __shfl_down(v, off, 64);
    __shared__ float red[4];
    int lane = threadIdx.x & 63, wv = threadIdx.x >> 6;
    if (lane == 0) red[wv] = v;
    __syncthreads();
    return red[0] + red[1] + red[2] + red[3];
}

// ---------------- conv1 via MFMA im2col: K = tap*8+ic (56, padded 64) -------
__global__ __launch_bounds__(256, 2)
void conv1_mfma(const float* __restrict__ x, const short* __restrict__ w1b,
                const float* __restrict__ b1, short* __restrict__ y) {
    constexpr int BT = 128, NR = 262;
    __shared__ short lxc[NR * 8];
    __shared__ short lw[64 * 64];
    int tid = threadIdx.x, b = blockIdx.z, t0 = blockIdx.x * BT;
    for (int i = tid; i < 512; i += 256) {
        int oc = i >> 3, c8 = i & 7;
        short8 v = *(const short8*)(w1b + oc * 64 + c8 * 8);
        *(short8*)(lw + oc * 64 + (c8 ^ (oc & 7)) * 8) = v;
    }
    for (int r = tid; r < NR; r += 256) {
        int g = 2 * t0 - 3 + r;
        short8 p;
        bool ok = (unsigned)g < (unsigned)T0;
        #pragma unroll
        for (int ic = 0; ic < 8; ic++) {
            float v = ok ? x[((size_t)b * 8 + ic) * T0 + g] : 0.f;
            p[ic] = f2bs(v);
        }
        *(short8*)(lxc + r * 8) = p;
    }
    __syncthreads();
    int wv = tid >> 6, lane = tid & 63, lm = lane & 31, lk = lane >> 5;
    int ml = wv * 32 + lm;
    f32x16 acc[2];
    #pragma unroll
    for (int oj = 0; oj < 2; oj++)
        #pragma unroll
        for (int r = 0; r < 16; r++) acc[oj][r] = 0.f;
    #pragma unroll
    for (int kc = 0; kc < 4; kc++) {
        int q = kc * 2 + lk;
        short8 a = *(const short8*)(lxc + (2 * ml + q) * 8);
        #pragma unroll
        for (int oj = 0; oj < 2; oj++) {
            int oc = oj * 32 + lm;
            short8 bf = *(const short8*)(lw + oc * 64 + (q ^ (oc & 7)) * 8);
            acc[oj] = __builtin_amdgcn_mfma_f32_32x32x16_bf16(a, bf, acc[oj], 0, 0, 0);
        }
    }
    #pragma unroll
    for (int oj = 0; oj < 2; oj++) {
        int oc = oj * 32 + lm;
        float bs = b1[oc];
        #pragma unroll
        for (int r = 0; r < 16; r++) {
            int t = t0 + wv * 32 + (r & 3) + 8 * (r >> 2) + 4 * lk;
            float v = fmaxf(acc[oj][r] + bs, 0.f);
            y[((size_t)b * T1 + t) * 64 + oc] = f2bs(v);
        }
    }
}

// --------- MFMA forward conv, full OC, weights staged in OCH halves ---------
template<int IC, int OC, int OCH, int TAPS, int PAD, int BT, int NW, bool RELU, bool F32OUT>
__global__ __launch_bounds__(NW * 64, 2)
void conv_mfma_fwd_full(const short* __restrict__ x, const short* __restrict__ wb,
                        const float* __restrict__ bias, void* __restrict__ yout,
                        const short* __restrict__ zb, int Tin, int Tout) {
    constexpr int C8 = IC / 8;
    constexpr int NR = 2 * (BT - 1) + TAPS;
    __shared__ short lw[TAPS * OCH * IC];
    __shared__ short lx[NR * IC];
    const int tid = threadIdx.x;
    const int b   = blockIdx.z;
    const int t0  = blockIdx.x * BT;
    const int r0  = 2 * t0 - PAD;
    const short* xg = x + (size_t)b * Tin * IC;
    for (int idx = tid; idx < NR * C8; idx += NW * 64) {
        int row = idx / C8, c8 = idx - row * C8;
        int gr = r0 + row;
        int sc8 = c8 ^ ((row >> 1) & (C8 - 1));
        const short* src = ((unsigned)gr < (unsigned)Tin)
            ? xg + (size_t)gr * IC + sc8 * 8 : zb;
        gload_lds16(src, lx + idx * 8);
    }
    const int wv = tid >> 6, lane = tid & 63;
    const int tl = wv * 32;
    const int lm = lane & 31, lk = lane >> 5;

    #pragma unroll
    for (int h = 0; h < OC / OCH; h++) {
        const int ocg = h * OCH;
        for (int i = tid; i < TAPS * OCH * C8; i += NW * 64) {
            int tap = i / (OCH * C8), rem = i - tap * OCH * C8;
            int ocl = rem / C8, d = rem - ocl * C8;
            int sc8 = d ^ (ocl & (C8 - 1));
            gload_lds16(wb + ((size_t)tap * OC + ocg + ocl) * IC + sc8 * 8,
                        lw + i * 8);
        }
        __syncthreads();                      // lw(h) ready (h==0: also lx)

        f32x16 acc[OCH / 32];
        #pragma unroll
        for (int oj = 0; oj < OCH / 32; oj++)
            #pragma unroll
            for (int r = 0; r < 16; r++) acc[oj][r] = 0.f;
        #pragma unroll
        for (int tap = 0; tap < TAPS; tap++) {
            #pragma unroll
            for (int kc = 0; kc < IC / 16; kc++) {
                int row = 2 * (tl + lm) + tap;
                int c8  = kc * 2 + lk;
                short8 a = *(const short8*)(lx + row * IC +
                                            (c8 ^ ((row >> 1) & (C8 - 1))) * 8);
                #pragma unroll
                for (int oj = 0; oj < OCH / 32; oj++) {
                    int ocl = oj * 32 + lm;
                    short8 bf = *(const short8*)(lw + (tap * OCH + ocl) * IC +
                                                 (c8 ^ (ocl & (C8 - 1))) * 8);
                    acc[oj] = __builtin_amdgcn_mfma_f32_32x32x16_bf16(a, bf, acc[oj], 0, 0, 0);
                }
            }
        }
        #pragma unroll
        for (int oj = 0; oj < OCH / 32; oj++) {
            int oc = ocg + oj * 32 + lm;
            float bs = bias[oc];
            #pragma unroll
            for (int r = 0; r < 16; r++) {
                int t = t0 + tl + (r & 3) + 8 * (r >> 2) + 4 * lk;
                float v = acc[oj][r] + bs;
                if (RELU) v = fmaxf(v, 0.f);
                if (F32OUT)
                    ((float*)yout)[((size_t)b * Tout + t) * OC + oc] = v;
                else
                    ((short*)yout)[((size_t)b * Tout + t) * OC + oc] = f2bs(v);
            }
        }
        if (h + 1 < OC / OCH) __syncthreads();  // lw reads done before restage
    }
}

// --------- MFMA conv-transpose, full OC, weights staged in OCH halves -------
template<int IC, int OC, int OCH, int BT, int NW, bool RELU>
__global__ __launch_bounds__(NW * 64, 2)
void conv_mfma_t_full(const short* __restrict__ x, const short* __restrict__ wb,
                      const float* __restrict__ bias, short* __restrict__ y,
                      const short* __restrict__ zb, int Tin) {
    constexpr int C8 = IC / 8;
    constexpr int NR = BT + 2;
    __shared__ short lw[4 * OCH * IC];
    __shared__ short lx[NR * IC];
    const int tid = threadIdx.x;
    const int b   = blockIdx.z;
    const int m0  = blockIdx.x * BT;
    const int r0  = m0 - 1;
    const short* xg = x + (size_t)b * Tin * IC;
    for (int idx = tid; idx < NR * C8; idx += NW * 64) {
        int row = idx / C8, c8 = idx - row * C8;
        int gr = r0 + row;
        int sc8 = c8 ^ ((row >> 1) & (C8 - 1));
        const short* src = ((unsigned)gr < (unsigned)Tin)
            ? xg + (size_t)gr * IC + sc8 * 8 : zb;
        gload_lds16(src, lx + idx * 8);
    }
    const int wv = tid >> 6, lane = tid & 63;
    const int ml = wv * 32;
    const int lm = lane & 31, lk = lane >> 5;
    int Tout = 2 * Tin;

    #pragma unroll
    for (int h = 0; h < OC / OCH; h++) {
        const int ocg = h * OCH;
        for (int i = tid; i < 4 * OCH * C8; i += NW * 64) {
            int k = i / (OCH * C8), rem = i - k * OCH * C8;
            int ocl = rem / C8, d = rem - ocl * C8;
            int sc8 = d ^ (ocl & (C8 - 1));
            gload_lds16(wb + ((size_t)k * OC + ocg + ocl) * IC + sc8 * 8,
                        lw + i * 8);
        }
        __syncthreads();                      // lw(h) ready (h==0: also lx)

        f32x16 accE[OCH / 32], accO[OCH / 32];
        #pragma unroll
        for (int oj = 0; oj < OCH / 32; oj++)
            #pragma unroll
            for (int r = 0; r < 16; r++) { accE[oj][r] = 0.f; accO[oj][r] = 0.f; }
        #pragma unroll
        for (int kc = 0; kc < IC / 16; kc++) {
            int c8 = kc * 2 + lk;
            int rA = ml + lm;
            short8 a_m1, a_0, a_p1;
            {
                int row = rA;
                a_m1 = *(const short8*)(lx + row * IC + (c8 ^ ((row >> 1) & (C8 - 1))) * 8);
                row = rA + 1;
                a_0  = *(const short8*)(lx + row * IC + (c8 ^ ((row >> 1) & (C8 - 1))) * 8);
                row = rA + 2;
                a_p1 = *(const short8*)(lx + row * IC + (c8 ^ ((row >> 1) & (C8 - 1))) * 8);
            }
            #pragma unroll
            for (int oj = 0; oj < OCH / 32; oj++) {
                int ocl = oj * 32 + lm;
                int sw = (c8 ^ (ocl & (C8 - 1))) * 8;
                short8 w0 = *(const short8*)(lw + ((0 * OCH + ocl) * IC) + sw);
                short8 w1 = *(const short8*)(lw + ((1 * OCH + ocl) * IC) + sw);
                short8 w2 = *(const short8*)(lw + ((2 * OCH + ocl) * IC) + sw);
                short8 w3 = *(const short8*)(lw + ((3 * OCH + ocl) * IC) + sw);
                accE[oj] = __builtin_amdgcn_mfma_f32_32x32x16_bf16(a_0,  w1, accE[oj], 0, 0, 0);
                accE[oj] = __builtin_amdgcn_mfma_f32_32x32x16_bf16(a_m1, w3, accE[oj], 0, 0, 0);
                accO[oj] = __builtin_amdgcn_mfma_f32_32x32x16_bf16(a_p1, w0, accO[oj], 0, 0, 0);
                accO[oj] = __builtin_amdgcn_mfma_f32_32x32x16_bf16(a_0,  w2, accO[oj], 0, 0, 0);
            }
        }
        #pragma unroll
        for (int oj = 0; oj < OCH / 32; oj++) {
            int oc = ocg + oj * 32 + lm;
            float bs = bias[oc];
            #pragma unroll
            for (int r = 0; r < 16; r++) {
                int m = m0 + ml + (r & 3) + 8 * (r >> 2) + 4 * lk;
                float ve = accE[oj][r] + bs;
                float vo = accO[oj][r] + bs;
                if (RELU) { ve = fmaxf(ve, 0.f); vo = fmaxf(vo, 0.f); }
                short* yp = y + ((size_t)b * Tout + 2 * m) * OC + oc;
                yp[0]  = f2bs(ve);
                yp[OC] = f2bs(vo);
            }
        }
        if (h + 1 < OC / OCH) __syncthreads();  // lw reads done before restage
    }
}

// ---- convT3 (64->8) + recon MSE via 16x16x32 MFMA im2col (K=192), BT=256 ---
__global__ __launch_bounds__(256, 2)
void convt3_loss(const short* __restrict__ r2, const short* __restrict__ w3m,
                 const float* __restrict__ db3, const float* __restrict__ x,
                 const short* __restrict__ zb, float* __restrict__ acc) {
    constexpr int BT = 256, NR = 258;
    __shared__ short lr[NR * 64];      // rows m0-1..m0+256, slot c8 ^= (r&7)
    __shared__ short lw[16 * 200];     // [n][k], stride 200
    __shared__ float lxt[8 * 512];     // x[oc][2*m0 .. 2*m0+511]
    int tid = threadIdx.x, b = blockIdx.z, m0 = blockIdx.x * BT;
    for (int i = tid; i < 384; i += 256) {
        int n = i / 24, kc = i - n * 24;
        *(short8*)(lw + n * 200 + kc * 8) = *(const short8*)(w3m + n * 192 + kc * 8);
    }
    const short* rb = r2 + (size_t)b * T1 * 64;
    for (int i = tid; i < NR * 8; i += 256) {
        int r = i >> 3, c8 = i & 7;
        int g = m0 - 1 + r;
        int sc8 = c8 ^ (r & 7);
        const short* src = ((unsigned)g < (unsigned)T1)
            ? rb + (size_t)g * 64 + sc8 * 8 : zb;
        gload_lds16(src, lr + i * 8);
    }
    const float* xb = x + (size_t)b * 8 * T0;
    for (int i = tid; i < 1024; i += 256) {
        int oc = i >> 7, c4 = (i & 127) * 4;
        gload_lds16(xb + (size_t)oc * T0 + 2 * m0 + c4, lxt + i * 4);
    }
    __syncthreads();
    int wv = tid >> 6, lane = tid & 63;
    int row16 = lane & 15, quad = lane >> 4;
    short8 bfr[6];
    #pragma unroll
    for (int kb = 0; kb < 6; kb++)
        bfr[kb] = *(const short8*)(lw + row16 * 200 + kb * 32 + quad * 8);
    f32x4 accv[4];
    #pragma unroll
    for (int rg = 0; rg < 4; rg++) accv[rg] = (f32x4){0.f, 0.f, 0.f, 0.f};
    #pragma unroll
    for (int kb = 0; kb < 6; kb++) {
        int kg = kb * 32 + quad * 8;
        int ro = kg >> 6, c8 = (kg >> 3) & 7;
        #pragma unroll
        for (int rg = 0; rg < 4; rg++) {     // 4 independent MFMA chains
            int r = wv * 64 + rg * 16 + row16 + ro;
            short8 a = *(const short8*)(lr + r * 64 + (c8 ^ (r & 7)) * 8);
            accv[rg] = __builtin_amdgcn_mfma_f32_16x16x32_bf16(a, bfr[kb], accv[rg], 0, 0, 0);
        }
    }
    int oc = row16 & 7, par = row16 >> 3;
    float bs = db3[oc];
    float s = 0.f;
    #pragma unroll
    for (int rg = 0; rg < 4; rg++)
        #pragma unroll
        for (int reg = 0; reg < 4; reg++) {
            int ml = wv * 64 + rg * 16 + quad * 4 + reg;
            float v = accv[rg][reg] + bs;
            float d = v - lxt[oc * 512 + 2 * ml + par];
            s += d * d;
        }
    s = block_sum256(s);
    if (tid == 0) atomicAdd(acc + 1, s);
}

// -------- prep: accumulators, codebook norms+bf16, weight transposes --------
// NOTE: c2 now stores 0.5*||c||^2 (exact pow2 scale; argmin order and ties
// identical since fl(a/2 - b/2) = fl(a-b)/2).
__global__ void prep_kernel(const float* __restrict__ cb, const float* __restrict__ w1,
                            const float* __restrict__ w2, const float* __restrict__ w3,
                            const float* __restrict__ dw1, const float* __restrict__ dw2,
                            const float* __restrict__ dw3,
                            float* __restrict__ c2, float* __restrict__ cond,
                            float* __restrict__ acc,
                            short* __restrict__ wb2, short* __restrict__ wb3,
                            short* __restrict__ wT1, short* __restrict__ wT2,
                            short* __restrict__ cbbf, short* __restrict__ w1b,
                            short* __restrict__ w3m, short* __restrict__ zb) {
    int i = blockIdx.x * 256 + threadIdx.x;
    if (i < 8) acc[i] = 0.f;
    if (i < 128) zb[i] = (short)0;             // OOB-halo zero source
    if (i < 1024) cond[i] = 0.f;
    if (i < NCODES) {
        float s = 0.f;
        #pragma unroll
        for (int d = 0; d < EDIM; d++) { float v = cb[i * EDIM + d]; s += v * v; }
        c2[i] = 0.5f * s;
    }
    if (i < 32768) cbbf[i] = f2bs(cb[i]);      // [c][d] bf16
    if (i < 4096) {                            // w1b[oc][k], k=tap*8+ic, pad 0
        int oc = i >> 6, k = i & 63;
        int ic = k & 7, q = k >> 3;
        w1b[i] = (q < 7) ? f2bs(w1[((size_t)oc * 8 + ic) * 7 + q]) : (short)0;
    }
    if (i < 3072) {                            // w3m[n][k], K=192 im2col B
        int n = i / 192, k = i - (i / 192) * 192;
        int oc = n & 7;
        float v = 0.f;
        if (n < 8) {
            if (k < 64)       v = dw3[((size_t)k * 8 + oc) * 4 + 3];
            else if (k < 128) v = dw3[((size_t)(k - 64) * 8 + oc) * 4 + 1];
        } else {
            if (k >= 128)     v = dw3[((size_t)(k - 128) * 8 + oc) * 4 + 0];
            else if (k >= 64) v = dw3[((size_t)(k - 64) * 8 + oc) * 4 + 2];
        }
        w3m[i] = f2bs(v);
    }
    if (i < 40960) {
        int tap = i / 8192, r = i - tap * 8192;
        int oc = r >> 6, ic = r & 63;
        wb2[i] = f2bs(w2[((size_t)oc * 64 + ic) * 5 + tap]);
    }
    if (i < 24576) {
        int tap = i / 8192, r = i - tap * 8192;
        int oc = r >> 7, ic = r & 127;
        wb3[i] = f2bs(w3[((size_t)oc * 128 + ic) * 3 + tap]);
    }
    if (i < 32768) {
        int k = i / 8192, r = i - k * 8192;
        int oc = r >> 6, ic = r & 63;
        wT1[i] = f2bs(dw1[((size_t)ic * 128 + oc) * 4 + k]);
    }
    if (i < 32768) {
        int k = i / 8192, r = i - k * 8192;
        int oc = r >> 7, ic = r & 127;
        wT2[i] = f2bs(dw2[((size_t)ic * 64 + oc) * 4 + k]);
    }
}

// -------- fused conv3 (128->64, k3 s2 p1) + VQ argmin + zq/cond/vql ---------
// r24 form; distance-phase argmin now float+index (4 VALU/candidate vs 8
// packed ops); butterfly does (d,idx) lexicographic tie-break = identical
// first-index-on-tie semantics.
__global__ __launch_bounds__(256, 2)
void conv3_quant(const short* __restrict__ a2, const short* __restrict__ wb3,
                 const float* __restrict__ b3, const float* __restrict__ cb,
                 const short* __restrict__ cbbf, const float* __restrict__ c2g,
                 const short* __restrict__ zb, short* __restrict__ zq,
                 float* __restrict__ cond, float* __restrict__ accg) {
    constexpr int IC = 128, C8 = IC / 8;       // 16
    constexpr int BT = 128;
    constexpr int NR = 2 * (BT - 1) + 3;       // 257
    __shared__ short lx[NR * IC];              // 65792 B; reused: lzq 16KB + lcb 32KB
    __shared__ float lc2[NCODES];
    __shared__ int   ibuf[BT];
    __shared__ float scr[4 * 64];
    int tid = threadIdx.x, b = blockIdx.z, t0 = blockIdx.x * BT;
    int r0 = 2 * t0 - 1;                       // PAD = 1
    for (int i = tid; i < NCODES; i += 256) lc2[i] = c2g[i];
    const short* xg = a2 + (size_t)b * T2 * IC;
    for (int idx = tid; idx < NR * C8; idx += 256) {
        int row = idx >> 4, c8 = idx & 15;
        int gr = r0 + row;
        int sc8 = c8 ^ ((row >> 1) & 15);
        const short* src = ((unsigned)gr < (unsigned)T2)
            ? xg + (size_t)gr * IC + sc8 * 8 : zb;
        gload_lds16(src, lx + idx * 8);
    }
    __syncthreads();

    int wv = tid >> 6, lane = tid & 63, lm = lane & 31, lk = lane >> 5;
    int tl = wv * 32;
    f32x16 acc[2];
    #pragma unroll
    for (int oj = 0; oj < 2; oj++)
        #pragma unroll
        for (int r = 0; r < 16; r++) acc[oj][r] = 0.f;
    #pragma unroll
    for (int tap = 0; tap < 3; tap++) {
        #pragma unroll
        for (int kc = 0; kc < 8; kc++) {
            int row = 2 * (tl + lm) + tap;
            int c8  = kc * 2 + lk;
            short8 a = *(const short8*)(lx + row * IC + (c8 ^ ((row >> 1) & 15)) * 8);
            #pragma unroll
            for (int oj = 0; oj < 2; oj++) {
                short8 bf = *(const short8*)(wb3 +
                    ((size_t)tap * 64 + oj * 32 + lm) * IC + c8 * 8);
                acc[oj] = __builtin_amdgcn_mfma_f32_32x32x16_bf16(a, bf, acc[oj], 0, 0, 0);
            }
        }
    }
    // fold bias in: acc now holds z_e fp32 for (t = t0+tl+i, oc = oj*32+lm)
    float bs0 = b3[lm], bs1 = b3[32 + lm];
    #pragma unroll
    for (int r = 0; r < 16; r++) { acc[0][r] += bs0; acc[1][r] += bs1; }
    __syncthreads();                           // all lx reads done -> reuse

    // bf16 z_e tile into reused lx: lzq[t][d] (16KB), slot c8 ^= (t&7)
    short* lzq = lx;
    short* lcb = lx + 8192;                    // 32KB codebook-half region
    #pragma unroll
    for (int oj = 0; oj < 2; oj++) {
        int oc = oj * 32 + lm;
        #pragma unroll
        for (int r = 0; r < 16; r++) {
            int tloc = tl + (r & 3) + 8 * (r >> 2) + 4 * lk;
            lzq[tloc * 64 + (((oc >> 3) ^ (tloc & 7)) * 8) + (oc & 7)] = f2bs(acc[oj][r]);
        }
    }
    __syncthreads();

    // A-fragments from lzq
    int arow = wv * 32 + lm;
    short8 afr[4];
    #pragma unroll
    for (int kc = 0; kc < 4; kc++) {
        int c8 = kc * 2 + lk;
        afr[kc] = *(const short8*)(lzq + arow * 64 + ((c8 ^ (arow & 7)) * 8));
    }
    // distance MFMA + float/index argmin; codebook staged LDS-half at a time
    f32x16 bestd;
    u32x16 bidx;
    #pragma unroll
    for (int r = 0; r < 16; r++) { bestd[r] = 3.402823466e38f; bidx[r] = 0u; }
    for (int half = 0; half < 2; half++) {
        // stage 256 codes (32KB): LDS[row][s] = G[half*256+row][s ^ (row&7)]
        for (int idx = tid; idx < 2048; idx += 256) {
            int row = idx >> 3, s = idx & 7;
            gload_lds16(cbbf + ((size_t)(half * 256 + row)) * 64 + ((s ^ (row & 7)) * 8),
                        lcb + idx * 8);
        }
        __syncthreads();                       // staging visible
        for (int ct8 = 0; ct8 < 8; ct8++) {
            int ct = half * 8 + ct8;
            f32x16 aq;
            #pragma unroll
            for (int r = 0; r < 16; r++) aq[r] = 0.f;
            int row = ct8 * 32 + lm;           // row within the staged half
            #pragma unroll
            for (int kc = 0; kc < 4; kc++) {
                int s = lk + 2 * kc;           // 16B slot within the 128B row
                short8 bf = *(const short8*)(lcb + row * 64 + ((s ^ (row & 7)) * 8));
                aq = __builtin_amdgcn_mfma_f32_32x32x16_bf16(afr[kc], bf, aq, 0, 0, 0);
            }
            unsigned cidx = (unsigned)(ct * 32 + lm);
            float c2h = lc2[cidx];             // 0.5*||c||^2
            #pragma unroll
            for (int r = 0; r < 16; r++) {
                float sd = c2h - aq[r];        // 0.5*(||c||^2 - 2 z.c), same order
                bool lt = sd < bestd[r];
                bestd[r] = lt ? sd : bestd[r];
                bidx[r]  = lt ? cidx : bidx[r];
            }
        }
        __syncthreads();                       // half reads done before overwrite
    }
    #pragma unroll
    for (int r = 0; r < 16; r++) {
        float d = bestd[r]; unsigned ix = bidx[r];
        #pragma unroll
        for (int mk = 1; mk < 32; mk <<= 1) {
            float od = __shfl_xor(d, mk, 64);
            unsigned oi = (unsigned)__shfl_xor((int)ix, mk, 64);
            bool take = (od < d) || (od == d && oi < ix);
            d  = take ? od : d;
            ix = take ? oi : ix;
        }
        if (lm == 0) ibuf[wv * 32 + (r & 3) + 8 * (r >> 2) + 4 * lk] = (int)ix;
    }
    __syncthreads();

    // epilogue: zq (bf16 codebook rows), vq loss vs fp32 z_e regs, cond sums
    float vql = 0.f, cpart0 = 0.f, cpart1 = 0.f;
    short* zqb = zq + ((size_t)(b * T3 + t0)) * 64;
    #pragma unroll
    for (int r = 0; r < 16; r++) {
        int tloc = tl + (r & 3) + 8 * (r >> 2) + 4 * lk;
        int code = ibuf[tloc];
        const float* cv = cb + (size_t)code * 64;
        float c0 = cv[lm], c1 = cv[32 + lm];
        float d0 = acc[0][r] - c0, d1 = acc[1][r] - c1;
        vql += d0 * d0 + d1 * d1;
        cpart0 += c0; cpart1 += c1;
        zqb[(size_t)tloc * 64 + lm]      = f2bs(c0);
        zqb[(size_t)tloc * 64 + 32 + lm] = f2bs(c1);
    }
    cpart0 += __shfl_down(cpart0, 32, 64);
    cpart1 += __shfl_down(cpart1, 32, 64);
    if (lk == 0) { scr[wv * 64 + lm] = cpart0; scr[wv * 64 + 32 + lm] = cpart1; }
    __syncthreads();
    if (tid < 64) {
        float s = scr[tid] + scr[64 + tid] + scr[128 + tid] + scr[192 + tid];
        atomicAdd(cond + b * 64 + tid, s);
    }
    vql = block_sum256(vql);
    if (tid == 0) atomicAdd(accg, vql);
}

__global__ void fin_kernel(const float* __restrict__ cond,
                           const float* __restrict__ acc, float* __restrict__ out) {
    int i = threadIdx.x;   // 1024 threads
    out[i] = cond[i] * (1.f / (float)T3);
    if (i == 0) {
        float vq = acc[0] * (1.f / 4194304.f);   // B*D*T3
        out[1024] = vq;
        out[1025] = vq;
        out[1026] = acc[1] * (1.f / 4194304.f);  // B*C0*T0
    }
}

extern "C" void kernel_launch(void* const* d_in, const int* in_sizes, int n_in,
                              void* d_out, int out_size, void* d_ws, size_t ws_size,
                              hipStream_t stream) {
    const float* x   = (const float*)d_in[0];
    const float* w1  = (const float*)d_in[1];
    const float* b1  = (const float*)d_in[2];
    const float* w2  = (const float*)d_in[3];
    const float* b2  = (const float*)d_in[4];
    const float* w3  = (const float*)d_in[5];
    const float* b3  = (const float*)d_in[6];
    const float* cb  = (const float*)d_in[7];
    const float* dw1 = (const float*)d_in[8];
    const float* db1 = (const float*)d_in[9];
    const float* dw2 = (const float*)d_in[10];
    const float* db2 = (const float*)d_in[11];
    const float* dw3 = (const float*)d_in[12];
    const float* db3 = (const float*)d_in[13];
    float* out = (float*)d_out;

    char* ws = (char*)d_ws;
    short* a1   = (short*)(ws);                    // [16][16384][64] bf16; later r2
    short* a2   = (short*)(ws + 33554432);         // [16][8192][128] bf16; later r1
    short* zq   = (short*)(ws + 83886080);         // [16][4096][64] bf16
    short* wb2  = (short*)(ws + 92274688);
    short* wb3  = (short*)(ws + 92356608);
    short* wT1  = (short*)(ws + 92405760);
    short* wT2  = (short*)(ws + 92471296);
    short* cbbf = (short*)(ws + 92536832);         // [512][64] bf16
    short* w1b  = (short*)(ws + 92602368);         // [64][64] bf16 (conv1 im2col)
    short* w3m  = (short*)(ws + 92610560);         // [16][192] bf16 (convt3 im2col)
    float* c2   = (float*)(ws + 92616704);
    float* cnd  = (float*)(ws + 92618752);
    float* acc  = (float*)(ws + 92622848);
    short* zb   = (short*)(ws + 92626944);         // 256B zero buffer (OOB halo)

    prep_kernel<<<160, 256, 0, stream>>>(cb, w1, w2, w3, dw1, dw2, dw3, c2, cnd,
                                         acc, wb2, wb3, wT1, wT2, cbbf, w1b, w3m,
                                         zb);
    conv1_mfma<<<dim3(T1 / 128, 1, NB), 256, 0, stream>>>(x, w1b, b1, a1);
    conv_mfma_fwd_full<64, 128, 64, 5, 2, 128, 4, true, false>
        <<<dim3(T2 / 128, 1, NB), 256, 0, stream>>>(a1, wb2, b2, a2, zb, T1, T2);
    conv3_quant<<<dim3(T3 / 128, 1, NB), 256, 0, stream>>>(a2, wb3, b3, cb, cbbf,
                                                           c2, zb, zq, cnd, acc);
    conv_mfma_t_full<64, 128, 64, 128, 4, true>
        <<<dim3(T3 / 128, 1, NB), 256, 0, stream>>>(zq, wT1, db1, a2, zb, T3);
    conv_mfma_t_full<128, 64, 32, 128, 4, true>
        <<<dim3(T2 / 128, 1, NB), 256, 0, stream>>>(a2, wT2, db2, a1, zb, T2);
    convt3_loss<<<dim3(T1 / 256, 1, NB), 256, 0, stream>>>(a1, w3m, db3, x, zb, acc);
    fin_kernel<<<1, 1024, 0, stream>>>(cnd, acc, out);
}

// Round 15
// 210.464 us; speedup vs baseline: 1.0359x; 1.0359x over previous
//
#include <hip/hip_runtime.h>
#include <hip/hip_bf16.h>

// VQ-VAE pipeline. Round 26: r25 REGRESSED (211.6 -> 218.0): splitting the
// packed argmin into float+index doubled live state (16->32 VGPR), VGPR
// 88->128, spilled (~15MB scratch traffic), bank conflicts 17x. The packed
// u32 representation IS the register budget. Revert to r24's packed argmin
// verbatim, keeping only the zero-register part of r25's idea: prep
// pre-scales c2 by 0.5 so the packed update is {s = c2h - aq; f2ord; and;
// or; umin} -- the v_fma (2.f*aq) is gone, -256 VALU ops/lane, state
// unchanged. Exact: pow2 scale preserves ordering AND the masked low-9-bit
// tie-collapse set (exponent-only shift, mantissa untouched, no denormals).
// Everything else = r24 (211.6us proven).
// Tripwires: VGPR 88, FETCH ~17MB, conflicts ~33k, absmax 6.103516e-05
// exact; if total >= 213 the r24 file is final.

#define NB 16
#define T0 32768
#define T1 16384
#define T2 8192
#define T3 4096
#define NCODES 512
#define EDIM 64

typedef __attribute__((ext_vector_type(8)))  short short8;
typedef __attribute__((ext_vector_type(16))) float f32x16;
typedef __attribute__((ext_vector_type(16))) unsigned u32x16;
typedef __attribute__((ext_vector_type(4)))  float f32x4;

__device__ __forceinline__ float b2f(short s) {
    unsigned u = ((unsigned)(unsigned short)s) << 16;
    float f; __builtin_memcpy(&f, &u, 4); return f;
}
__device__ __forceinline__ short f2bs(float f) {
    __hip_bfloat16 h = __float2bfloat16(f);
    short s; __builtin_memcpy(&s, &h, 2); return s;
}
// monotone float -> sortable unsigned
__device__ __forceinline__ unsigned f2ord(float s) {
    unsigned u = __float_as_uint(s);
    return u ^ ((unsigned)((int)u >> 31) | 0x80000000u);
}

// async 16B global->LDS copy (wave-uniform LDS base + lane*16; drained by
// the s_waitcnt vmcnt(0) that __syncthreads() emits)
__device__ __forceinline__ void gload_lds16(const void* g, void* l) {
    __builtin_amdgcn_global_load_lds(
        (const __attribute__((address_space(1))) void*)g,
        (__attribute__((address_space(3))) void*)l, 16, 0, 0);
}

__device__ __forceinline__ float block_sum256(float v) {
    #pragma unroll
    for (int off = 32; off > 0; off >>= 1) v += __shfl_down(v, off, 64);
    __shared__ float red[4];
    int lane = threadIdx.x & 63, wv = threadIdx.x >> 6;
    if (lane == 0) red[wv] = v;
    __syncthreads();
    return red[0] + red[1] + red[2] + red[3];
}

// ---------------- conv1 via MFMA im2col: K = tap*8+ic (56, padded 64) -------
__global__ __launch_bounds__(256, 2)
void conv1_mfma(const float* __restrict__ x, const short* __restrict__ w1b,
                const float* __restrict__ b1, short* __restrict__ y) {
    constexpr int BT = 128, NR = 262;
    __shared__ short lxc[NR * 8];
    __shared__ short lw[64 * 64];
    int tid = threadIdx.x, b = blockIdx.z, t0 = blockIdx.x * BT;
    for (int i = tid; i < 512; i += 256) {
        int oc = i >> 3, c8 = i & 7;
        short8 v = *(const short8*)(w1b + oc * 64 + c8 * 8);
        *(short8*)(lw + oc * 64 + (c8 ^ (oc & 7)) * 8) = v;
    }
    for (int r = tid; r < NR; r += 256) {
        int g = 2 * t0 - 3 + r;
        short8 p;
        bool ok = (unsigned)g < (unsigned)T0;
        #pragma unroll
        for (int ic = 0; ic < 8; ic++) {
            float v = ok ? x[((size_t)b * 8 + ic) * T0 + g] : 0.f;
            p[ic] = f2bs(v);
        }
        *(short8*)(lxc + r * 8) = p;
    }
    __syncthreads();
    int wv = tid >> 6, lane = tid & 63, lm = lane & 31, lk = lane >> 5;
    int ml = wv * 32 + lm;
    f32x16 acc[2];
    #pragma unroll
    for (int oj = 0; oj < 2; oj++)
        #pragma unroll
        for (int r = 0; r < 16; r++) acc[oj][r] = 0.f;
    #pragma unroll
    for (int kc = 0; kc < 4; kc++) {
        int q = kc * 2 + lk;
        short8 a = *(const short8*)(lxc + (2 * ml + q) * 8);
        #pragma unroll
        for (int oj = 0; oj < 2; oj++) {
            int oc = oj * 32 + lm;
            short8 bf = *(const short8*)(lw + oc * 64 + (q ^ (oc & 7)) * 8);
            acc[oj] = __builtin_amdgcn_mfma_f32_32x32x16_bf16(a, bf, acc[oj], 0, 0, 0);
        }
    }
    #pragma unroll
    for (int oj = 0; oj < 2; oj++) {
        int oc = oj * 32 + lm;
        float bs = b1[oc];
        #pragma unroll
        for (int r = 0; r < 16; r++) {
            int t = t0 + wv * 32 + (r & 3) + 8 * (r >> 2) + 4 * lk;
            float v = fmaxf(acc[oj][r] + bs, 0.f);
            y[((size_t)b * T1 + t) * 64 + oc] = f2bs(v);
        }
    }
}

// --------- MFMA forward conv, full OC, weights staged in OCH halves ---------
template<int IC, int OC, int OCH, int TAPS, int PAD, int BT, int NW, bool RELU, bool F32OUT>
__global__ __launch_bounds__(NW * 64, 2)
void conv_mfma_fwd_full(const short* __restrict__ x, const short* __restrict__ wb,
                        const float* __restrict__ bias, void* __restrict__ yout,
                        const short* __restrict__ zb, int Tin, int Tout) {
    constexpr int C8 = IC / 8;
    constexpr int NR = 2 * (BT - 1) + TAPS;
    __shared__ short lw[TAPS * OCH * IC];
    __shared__ short lx[NR * IC];
    const int tid = threadIdx.x;
    const int b   = blockIdx.z;
    const int t0  = blockIdx.x * BT;
    const int r0  = 2 * t0 - PAD;
    const short* xg = x + (size_t)b * Tin * IC;
    for (int idx = tid; idx < NR * C8; idx += NW * 64) {
        int row = idx / C8, c8 = idx - row * C8;
        int gr = r0 + row;
        int sc8 = c8 ^ ((row >> 1) & (C8 - 1));
        const short* src = ((unsigned)gr < (unsigned)Tin)
            ? xg + (size_t)gr * IC + sc8 * 8 : zb;
        gload_lds16(src, lx + idx * 8);
    }
    const int wv = tid >> 6, lane = tid & 63;
    const int tl = wv * 32;
    const int lm = lane & 31, lk = lane >> 5;

    #pragma unroll
    for (int h = 0; h < OC / OCH; h++) {
        const int ocg = h * OCH;
        for (int i = tid; i < TAPS * OCH * C8; i += NW * 64) {
            int tap = i / (OCH * C8), rem = i - tap * OCH * C8;
            int ocl = rem / C8, d = rem - ocl * C8;
            int sc8 = d ^ (ocl & (C8 - 1));
            gload_lds16(wb + ((size_t)tap * OC + ocg + ocl) * IC + sc8 * 8,
                        lw + i * 8);
        }
        __syncthreads();                      // lw(h) ready (h==0: also lx)

        f32x16 acc[OCH / 32];
        #pragma unroll
        for (int oj = 0; oj < OCH / 32; oj++)
            #pragma unroll
            for (int r = 0; r < 16; r++) acc[oj][r] = 0.f;
        #pragma unroll
        for (int tap = 0; tap < TAPS; tap++) {
            #pragma unroll
            for (int kc = 0; kc < IC / 16; kc++) {
                int row = 2 * (tl + lm) + tap;
                int c8  = kc * 2 + lk;
                short8 a = *(const short8*)(lx + row * IC +
                                            (c8 ^ ((row >> 1) & (C8 - 1))) * 8);
                #pragma unroll
                for (int oj = 0; oj < OCH / 32; oj++) {
                    int ocl = oj * 32 + lm;
                    short8 bf = *(const short8*)(lw + (tap * OCH + ocl) * IC +
                                                 (c8 ^ (ocl & (C8 - 1))) * 8);
                    acc[oj] = __builtin_amdgcn_mfma_f32_32x32x16_bf16(a, bf, acc[oj], 0, 0, 0);
                }
            }
        }
        #pragma unroll
        for (int oj = 0; oj < OCH / 32; oj++) {
            int oc = ocg + oj * 32 + lm;
            float bs = bias[oc];
            #pragma unroll
            for (int r = 0; r < 16; r++) {
                int t = t0 + tl + (r & 3) + 8 * (r >> 2) + 4 * lk;
                float v = acc[oj][r] + bs;
                if (RELU) v = fmaxf(v, 0.f);
                if (F32OUT)
                    ((float*)yout)[((size_t)b * Tout + t) * OC + oc] = v;
                else
                    ((short*)yout)[((size_t)b * Tout + t) * OC + oc] = f2bs(v);
            }
        }
        if (h + 1 < OC / OCH) __syncthreads();  // lw reads done before restage
    }
}

// --------- MFMA conv-transpose, full OC, weights staged in OCH halves -------
template<int IC, int OC, int OCH, int BT, int NW, bool RELU>
__global__ __launch_bounds__(NW * 64, 2)
void conv_mfma_t_full(const short* __restrict__ x, const short* __restrict__ wb,
                      const float* __restrict__ bias, short* __restrict__ y,
                      const short* __restrict__ zb, int Tin) {
    constexpr int C8 = IC / 8;
    constexpr int NR = BT + 2;
    __shared__ short lw[4 * OCH * IC];
    __shared__ short lx[NR * IC];
    const int tid = threadIdx.x;
    const int b   = blockIdx.z;
    const int m0  = blockIdx.x * BT;
    const int r0  = m0 - 1;
    const short* xg = x + (size_t)b * Tin * IC;
    for (int idx = tid; idx < NR * C8; idx += NW * 64) {
        int row = idx / C8, c8 = idx - row * C8;
        int gr = r0 + row;
        int sc8 = c8 ^ ((row >> 1) & (C8 - 1));
        const short* src = ((unsigned)gr < (unsigned)Tin)
            ? xg + (size_t)gr * IC + sc8 * 8 : zb;
        gload_lds16(src, lx + idx * 8);
    }
    const int wv = tid >> 6, lane = tid & 63;
    const int ml = wv * 32;
    const int lm = lane & 31, lk = lane >> 5;
    int Tout = 2 * Tin;

    #pragma unroll
    for (int h = 0; h < OC / OCH; h++) {
        const int ocg = h * OCH;
        for (int i = tid; i < 4 * OCH * C8; i += NW * 64) {
            int k = i / (OCH * C8), rem = i - k * OCH * C8;
            int ocl = rem / C8, d = rem - ocl * C8;
            int sc8 = d ^ (ocl & (C8 - 1));
            gload_lds16(wb + ((size_t)k * OC + ocg + ocl) * IC + sc8 * 8,
                        lw + i * 8);
        }
        __syncthreads();                      // lw(h) ready (h==0: also lx)

        f32x16 accE[OCH / 32], accO[OCH / 32];
        #pragma unroll
        for (int oj = 0; oj < OCH / 32; oj++)
            #pragma unroll
            for (int r = 0; r < 16; r++) { accE[oj][r] = 0.f; accO[oj][r] = 0.f; }
        #pragma unroll
        for (int kc = 0; kc < IC / 16; kc++) {
            int c8 = kc * 2 + lk;
            int rA = ml + lm;
            short8 a_m1, a_0, a_p1;
            {
                int row = rA;
                a_m1 = *(const short8*)(lx + row * IC + (c8 ^ ((row >> 1) & (C8 - 1))) * 8);
                row = rA + 1;
                a_0  = *(const short8*)(lx + row * IC + (c8 ^ ((row >> 1) & (C8 - 1))) * 8);
                row = rA + 2;
                a_p1 = *(const short8*)(lx + row * IC + (c8 ^ ((row >> 1) & (C8 - 1))) * 8);
            }
            #pragma unroll
            for (int oj = 0; oj < OCH / 32; oj++) {
                int ocl = oj * 32 + lm;
                int sw = (c8 ^ (ocl & (C8 - 1))) * 8;
                short8 w0 = *(const short8*)(lw + ((0 * OCH + ocl) * IC) + sw);
                short8 w1 = *(const short8*)(lw + ((1 * OCH + ocl) * IC) + sw);
                short8 w2 = *(const short8*)(lw + ((2 * OCH + ocl) * IC) + sw);
                short8 w3 = *(const short8*)(lw + ((3 * OCH + ocl) * IC) + sw);
                accE[oj] = __builtin_amdgcn_mfma_f32_32x32x16_bf16(a_0,  w1, accE[oj], 0, 0, 0);
                accE[oj] = __builtin_amdgcn_mfma_f32_32x32x16_bf16(a_m1, w3, accE[oj], 0, 0, 0);
                accO[oj] = __builtin_amdgcn_mfma_f32_32x32x16_bf16(a_p1, w0, accO[oj], 0, 0, 0);
                accO[oj] = __builtin_amdgcn_mfma_f32_32x32x16_bf16(a_0,  w2, accO[oj], 0, 0, 0);
            }
        }
        #pragma unroll
        for (int oj = 0; oj < OCH / 32; oj++) {
            int oc = ocg + oj * 32 + lm;
            float bs = bias[oc];
            #pragma unroll
            for (int r = 0; r < 16; r++) {
                int m = m0 + ml + (r & 3) + 8 * (r >> 2) + 4 * lk;
                float ve = accE[oj][r] + bs;
                float vo = accO[oj][r] + bs;
                if (RELU) { ve = fmaxf(ve, 0.f); vo = fmaxf(vo, 0.f); }
                short* yp = y + ((size_t)b * Tout + 2 * m) * OC + oc;
                yp[0]  = f2bs(ve);
                yp[OC] = f2bs(vo);
            }
        }
        if (h + 1 < OC / OCH) __syncthreads();  // lw reads done before restage
    }
}

// ---- convT3 (64->8) + recon MSE via 16x16x32 MFMA im2col (K=192), BT=256 ---
__global__ __launch_bounds__(256, 2)
void convt3_loss(const short* __restrict__ r2, const short* __restrict__ w3m,
                 const float* __restrict__ db3, const float* __restrict__ x,
                 const short* __restrict__ zb, float* __restrict__ acc) {
    constexpr int BT = 256, NR = 258;
    __shared__ short lr[NR * 64];      // rows m0-1..m0+256, slot c8 ^= (r&7)
    __shared__ short lw[16 * 200];     // [n][k], stride 200
    __shared__ float lxt[8 * 512];     // x[oc][2*m0 .. 2*m0+511]
    int tid = threadIdx.x, b = blockIdx.z, m0 = blockIdx.x * BT;
    for (int i = tid; i < 384; i += 256) {
        int n = i / 24, kc = i - n * 24;
        *(short8*)(lw + n * 200 + kc * 8) = *(const short8*)(w3m + n * 192 + kc * 8);
    }
    const short* rb = r2 + (size_t)b * T1 * 64;
    for (int i = tid; i < NR * 8; i += 256) {
        int r = i >> 3, c8 = i & 7;
        int g = m0 - 1 + r;
        int sc8 = c8 ^ (r & 7);
        const short* src = ((unsigned)g < (unsigned)T1)
            ? rb + (size_t)g * 64 + sc8 * 8 : zb;
        gload_lds16(src, lr + i * 8);
    }
    const float* xb = x + (size_t)b * 8 * T0;
    for (int i = tid; i < 1024; i += 256) {
        int oc = i >> 7, c4 = (i & 127) * 4;
        gload_lds16(xb + (size_t)oc * T0 + 2 * m0 + c4, lxt + i * 4);
    }
    __syncthreads();
    int wv = tid >> 6, lane = tid & 63;
    int row16 = lane & 15, quad = lane >> 4;
    short8 bfr[6];
    #pragma unroll
    for (int kb = 0; kb < 6; kb++)
        bfr[kb] = *(const short8*)(lw + row16 * 200 + kb * 32 + quad * 8);
    f32x4 accv[4];
    #pragma unroll
    for (int rg = 0; rg < 4; rg++) accv[rg] = (f32x4){0.f, 0.f, 0.f, 0.f};
    #pragma unroll
    for (int kb = 0; kb < 6; kb++) {
        int kg = kb * 32 + quad * 8;
        int ro = kg >> 6, c8 = (kg >> 3) & 7;
        #pragma unroll
        for (int rg = 0; rg < 4; rg++) {     // 4 independent MFMA chains
            int r = wv * 64 + rg * 16 + row16 + ro;
            short8 a = *(const short8*)(lr + r * 64 + (c8 ^ (r & 7)) * 8);
            accv[rg] = __builtin_amdgcn_mfma_f32_16x16x32_bf16(a, bfr[kb], accv[rg], 0, 0, 0);
        }
    }
    int oc = row16 & 7, par = row16 >> 3;
    float bs = db3[oc];
    float s = 0.f;
    #pragma unroll
    for (int rg = 0; rg < 4; rg++)
        #pragma unroll
        for (int reg = 0; reg < 4; reg++) {
            int ml = wv * 64 + rg * 16 + quad * 4 + reg;
            float v = accv[rg][reg] + bs;
            float d = v - lxt[oc * 512 + 2 * ml + par];
            s += d * d;
        }
    s = block_sum256(s);
    if (tid == 0) atomicAdd(acc + 1, s);
}

// -------- prep: accumulators, codebook norms+bf16, weight transposes --------
// NOTE: c2 stores 0.5*||c||^2 (exact pow2 scale: ordering and the packed
// low-9-bit tie-collapse set are preserved -- exponent-only shift).
__global__ void prep_kernel(const float* __restrict__ cb, const float* __restrict__ w1,
                            const float* __restrict__ w2, const float* __restrict__ w3,
                            const float* __restrict__ dw1, const float* __restrict__ dw2,
                            const float* __restrict__ dw3,
                            float* __restrict__ c2, float* __restrict__ cond,
                            float* __restrict__ acc,
                            short* __restrict__ wb2, short* __restrict__ wb3,
                            short* __restrict__ wT1, short* __restrict__ wT2,
                            short* __restrict__ cbbf, short* __restrict__ w1b,
                            short* __restrict__ w3m, short* __restrict__ zb) {
    int i = blockIdx.x * 256 + threadIdx.x;
    if (i < 8) acc[i] = 0.f;
    if (i < 128) zb[i] = (short)0;             // OOB-halo zero source
    if (i < 1024) cond[i] = 0.f;
    if (i < NCODES) {
        float s = 0.f;
        #pragma unroll
        for (int d = 0; d < EDIM; d++) { float v = cb[i * EDIM + d]; s += v * v; }
        c2[i] = 0.5f * s;
    }
    if (i < 32768) cbbf[i] = f2bs(cb[i]);      // [c][d] bf16
    if (i < 4096) {                            // w1b[oc][k], k=tap*8+ic, pad 0
        int oc = i >> 6, k = i & 63;
        int ic = k & 7, q = k >> 3;
        w1b[i] = (q < 7) ? f2bs(w1[((size_t)oc * 8 + ic) * 7 + q]) : (short)0;
    }
    if (i < 3072) {                            // w3m[n][k], K=192 im2col B
        int n = i / 192, k = i - (i / 192) * 192;
        int oc = n & 7;
        float v = 0.f;
        if (n < 8) {
            if (k < 64)       v = dw3[((size_t)k * 8 + oc) * 4 + 3];
            else if (k < 128) v = dw3[((size_t)(k - 64) * 8 + oc) * 4 + 1];
        } else {
            if (k >= 128)     v = dw3[((size_t)(k - 128) * 8 + oc) * 4 + 0];
            else if (k >= 64) v = dw3[((size_t)(k - 64) * 8 + oc) * 4 + 2];
        }
        w3m[i] = f2bs(v);
    }
    if (i < 40960) {
        int tap = i / 8192, r = i - tap * 8192;
        int oc = r >> 6, ic = r & 63;
        wb2[i] = f2bs(w2[((size_t)oc * 64 + ic) * 5 + tap]);
    }
    if (i < 24576) {
        int tap = i / 8192, r = i - tap * 8192;
        int oc = r >> 7, ic = r & 127;
        wb3[i] = f2bs(w3[((size_t)oc * 128 + ic) * 3 + tap]);
    }
    if (i < 32768) {
        int k = i / 8192, r = i - k * 8192;
        int oc = r >> 6, ic = r & 63;
        wT1[i] = f2bs(dw1[((size_t)ic * 128 + oc) * 4 + k]);
    }
    if (i < 32768) {
        int k = i / 8192, r = i - k * 8192;
        int oc = r >> 7, ic = r & 127;
        wT2[i] = f2bs(dw2[((size_t)ic * 64 + oc) * 4 + k]);
    }
}

// -------- fused conv3 (128->64, k3 s2 p1) + VQ argmin + zq/cond/vql ---------
// r24 form (packed sortable-u32 argmin, 88 VGPR); only change: c2 is
// pre-halved so the packed update drops its v_fma (s = c2h - aq).
__global__ __launch_bounds__(256, 2)
void conv3_quant(const short* __restrict__ a2, const short* __restrict__ wb3,
                 const float* __restrict__ b3, const float* __restrict__ cb,
                 const short* __restrict__ cbbf, const float* __restrict__ c2g,
                 const short* __restrict__ zb, short* __restrict__ zq,
                 float* __restrict__ cond, float* __restrict__ accg) {
    constexpr int IC = 128, C8 = IC / 8;       // 16
    constexpr int BT = 128;
    constexpr int NR = 2 * (BT - 1) + 3;       // 257
    __shared__ short lx[NR * IC];              // 65792 B; reused: lzq 16KB + lcb 32KB
    __shared__ float lc2[NCODES];
    __shared__ int   ibuf[BT];
    __shared__ float scr[4 * 64];
    int tid = threadIdx.x, b = blockIdx.z, t0 = blockIdx.x * BT;
    int r0 = 2 * t0 - 1;                       // PAD = 1
    for (int i = tid; i < NCODES; i += 256) lc2[i] = c2g[i];
    const short* xg = a2 + (size_t)b * T2 * IC;
    for (int idx = tid; idx < NR * C8; idx += 256) {
        int row = idx >> 4, c8 = idx & 15;
        int gr = r0 + row;
        int sc8 = c8 ^ ((row >> 1) & 15);
        const short* src = ((unsigned)gr < (unsigned)T2)
            ? xg + (size_t)gr * IC + sc8 * 8 : zb;
        gload_lds16(src, lx + idx * 8);
    }
    __syncthreads();

    int wv = tid >> 6, lane = tid & 63, lm = lane & 31, lk = lane >> 5;
    int tl = wv * 32;
    f32x16 acc[2];
    #pragma unroll
    for (int oj = 0; oj < 2; oj++)
        #pragma unroll
        for (int r = 0; r < 16; r++) acc[oj][r] = 0.f;
    #pragma unroll
    for (int tap = 0; tap < 3; tap++) {
        #pragma unroll
        for (int kc = 0; kc < 8; kc++) {
            int row = 2 * (tl + lm) + tap;
            int c8  = kc * 2 + lk;
            short8 a = *(const short8*)(lx + row * IC + (c8 ^ ((row >> 1) & 15)) * 8);
            #pragma unroll
            for (int oj = 0; oj < 2; oj++) {
                short8 bf = *(const short8*)(wb3 +
                    ((size_t)tap * 64 + oj * 32 + lm) * IC + c8 * 8);
                acc[oj] = __builtin_amdgcn_mfma_f32_32x32x16_bf16(a, bf, acc[oj], 0, 0, 0);
            }
        }
    }
    // fold bias in: acc now holds z_e fp32 for (t = t0+tl+i, oc = oj*32+lm)
    float bs0 = b3[lm], bs1 = b3[32 + lm];
    #pragma unroll
    for (int r = 0; r < 16; r++) { acc[0][r] += bs0; acc[1][r] += bs1; }
    __syncthreads();                           // all lx reads done -> reuse

    // bf16 z_e tile into reused lx: lzq[t][d] (16KB), slot c8 ^= (t&7)
    short* lzq = lx;
    short* lcb = lx + 8192;                    // 32KB codebook-half region
    #pragma unroll
    for (int oj = 0; oj < 2; oj++) {
        int oc = oj * 32 + lm;
        #pragma unroll
        for (int r = 0; r < 16; r++) {
            int tloc = tl + (r & 3) + 8 * (r >> 2) + 4 * lk;
            lzq[tloc * 64 + (((oc >> 3) ^ (tloc & 7)) * 8) + (oc & 7)] = f2bs(acc[oj][r]);
        }
    }
    __syncthreads();

    // A-fragments from lzq
    int arow = wv * 32 + lm;
    short8 afr[4];
    #pragma unroll
    for (int kc = 0; kc < 4; kc++) {
        int c8 = kc * 2 + lk;
        afr[kc] = *(const short8*)(lzq + arow * 64 + ((c8 ^ (arow & 7)) * 8));
    }
    // distance MFMA + packed register argmin; codebook staged LDS-half at a time
    u32x16 bestp;
    #pragma unroll
    for (int r = 0; r < 16; r++) bestp[r] = 0xFFFFFFFFu;
    for (int half = 0; half < 2; half++) {
        // stage 256 codes (32KB): LDS[row][s] = G[half*256+row][s ^ (row&7)]
        for (int idx = tid; idx < 2048; idx += 256) {
            int row = idx >> 3, s = idx & 7;
            gload_lds16(cbbf + ((size_t)(half * 256 + row)) * 64 + ((s ^ (row & 7)) * 8),
                        lcb + idx * 8);
        }
        __syncthreads();                       // staging visible
        for (int ct8 = 0; ct8 < 8; ct8++) {
            int ct = half * 8 + ct8;
            f32x16 aq;
            #pragma unroll
            for (int r = 0; r < 16; r++) aq[r] = 0.f;
            int row = ct8 * 32 + lm;           // row within the staged half
            #pragma unroll
            for (int kc = 0; kc < 4; kc++) {
                int s = lk + 2 * kc;           // 16B slot within the 128B row
                short8 bf = *(const short8*)(lcb + row * 64 + ((s ^ (row & 7)) * 8));
                aq = __builtin_amdgcn_mfma_f32_32x32x16_bf16(afr[kc], bf, aq, 0, 0, 0);
            }
            unsigned cidx = (unsigned)(ct * 32 + lm);
            float c2h = lc2[cidx];             // 0.5*||c||^2
            #pragma unroll
            for (int r = 0; r < 16; r++) {
                float sd = c2h - aq[r];        // 0.5*(||c||^2 - 2 z.c): same order/ties
                unsigned p = (f2ord(sd) & 0xFFFFFE00u) | cidx;
                bestp[r] = (p < bestp[r]) ? p : bestp[r];
            }
        }
        __syncthreads();                       // half reads done before overwrite
    }
    #pragma unroll
    for (int r = 0; r < 16; r++) {
        unsigned p = bestp[r];
        #pragma unroll
        for (int mk = 1; mk < 32; mk <<= 1) {
            unsigned op = (unsigned)__shfl_xor((int)p, mk, 64);
            p = (op < p) ? op : p;
        }
        if (lm == 0) ibuf[wv * 32 + (r & 3) + 8 * (r >> 2) + 4 * lk] = (int)(p & 511u);
    }
    __syncthreads();

    // epilogue: zq (bf16 codebook rows), vq loss vs fp32 z_e regs, cond sums
    float vql = 0.f, cpart0 = 0.f, cpart1 = 0.f;
    short* zqb = zq + ((size_t)(b * T3 + t0)) * 64;
    #pragma unroll
    for (int r = 0; r < 16; r++) {
        int tloc = tl + (r & 3) + 8 * (r >> 2) + 4 * lk;
        int code = ibuf[tloc];
        const float* cv = cb + (size_t)code * 64;
        float c0 = cv[lm], c1 = cv[32 + lm];
        float d0 = acc[0][r] - c0, d1 = acc[1][r] - c1;
        vql += d0 * d0 + d1 * d1;
        cpart0 += c0; cpart1 += c1;
        zqb[(size_t)tloc * 64 + lm]      = f2bs(c0);
        zqb[(size_t)tloc * 64 + 32 + lm] = f2bs(c1);
    }
    cpart0 += __shfl_down(cpart0, 32, 64);
    cpart1 += __shfl_down(cpart1, 32, 64);
    if (lk == 0) { scr[wv * 64 + lm] = cpart0; scr[wv * 64 + 32 + lm] = cpart1; }
    __syncthreads();
    if (tid < 64) {
        float s = scr[tid] + scr[64 + tid] + scr[128 + tid] + scr[192 + tid];
        atomicAdd(cond + b * 64 + tid, s);
    }
    vql = block_sum256(vql);
    if (tid == 0) atomicAdd(accg, vql);
}

__global__ void fin_kernel(const float* __restrict__ cond,
                           const float* __restrict__ acc, float* __restrict__ out) {
    int i = threadIdx.x;   // 1024 threads
    out[i] = cond[i] * (1.f / (float)T3);
    if (i == 0) {
        float vq = acc[0] * (1.f / 4194304.f);   // B*D*T3
        out[1024] = vq;
        out[1025] = vq;
        out[1026] = acc[1] * (1.f / 4194304.f);  // B*C0*T0
    }
}

extern "C" void kernel_launch(void* const* d_in, const int* in_sizes, int n_in,
                              void* d_out, int out_size, void* d_ws, size_t ws_size,
                              hipStream_t stream) {
    const float* x   = (const float*)d_in[0];
    const float* w1  = (const float*)d_in[1];
    const float* b1  = (const float*)d_in[2];
    const float* w2  = (const float*)d_in[3];
    const float* b2  = (const float*)d_in[4];
    const float* w3  = (const float*)d_in[5];
    const float* b3  = (const float*)d_in[6];
    const float* cb  = (const float*)d_in[7];
    const float* dw1 = (const float*)d_in[8];
    const float* db1 = (const float*)d_in[9];
    const float* dw2 = (const float*)d_in[10];
    const float* db2 = (const float*)d_in[11];
    const float* dw3 = (const float*)d_in[12];
    const float* db3 = (const float*)d_in[13];
    float* out = (float*)d_out;

    char* ws = (char*)d_ws;
    short* a1   = (short*)(ws);                    // [16][16384][64] bf16; later r2
    short* a2   = (short*)(ws + 33554432);         // [16][8192][128] bf16; later r1
    short* zq   = (short*)(ws + 83886080);         // [16][4096][64] bf16
    short* wb2  = (short*)(ws + 92274688);
    short* wb3  = (short*)(ws + 92356608);
    short* wT1  = (short*)(ws + 92405760);
    short* wT2  = (short*)(ws + 92471296);
    short* cbbf = (short*)(ws + 92536832);         // [512][64] bf16
    short* w1b  = (short*)(ws + 92602368);         // [64][64] bf16 (conv1 im2col)
    short* w3m  = (short*)(ws + 92610560);         // [16][192] bf16 (convt3 im2col)
    float* c2   = (float*)(ws + 92616704);
    float* cnd  = (float*)(ws + 92618752);
    float* acc  = (float*)(ws + 92622848);
    short* zb   = (short*)(ws + 92626944);         // 256B zero buffer (OOB halo)

    prep_kernel<<<160, 256, 0, stream>>>(cb, w1, w2, w3, dw1, dw2, dw3, c2, cnd,
                                         acc, wb2, wb3, wT1, wT2, cbbf, w1b, w3m,
                                         zb);
    conv1_mfma<<<dim3(T1 / 128, 1, NB), 256, 0, stream>>>(x, w1b, b1, a1);
    conv_mfma_fwd_full<64, 128, 64, 5, 2, 128, 4, true, false>
        <<<dim3(T2 / 128, 1, NB), 256, 0, stream>>>(a1, wb2, b2, a2, zb, T1, T2);
    conv3_quant<<<dim3(T3 / 128, 1, NB), 256, 0, stream>>>(a2, wb3, b3, cb, cbbf,
                                                           c2, zb, zq, cnd, acc);
    conv_mfma_t_full<64, 128, 64, 128, 4, true>
        <<<dim3(T3 / 128, 1, NB), 256, 0, stream>>>(zq, wT1, db1, a2, zb, T3);
    conv_mfma_t_full<128, 64, 32, 128, 4, true>
        <<<dim3(T2 / 128, 1, NB), 256, 0, stream>>>(a2, wT2, db2, a1, zb, T2);
    convt3_loss<<<dim3(T1 / 256, 1, NB), 256, 0, stream>>>(a1, w3m, db3, x, zb, acc);
    fin_kernel<<<1, 1024, 0, stream>>>(cnd, acc, out);
}